// Round 1
// 498.675 us; speedup vs baseline: 1.0109x; 1.0109x over previous
//
#include <hip/hip_runtime.h>

typedef _Float16 h16;
typedef _Float16 h4 __attribute__((ext_vector_type(4)));
typedef _Float16 h8 __attribute__((ext_vector_type(8)));
typedef float f4 __attribute__((ext_vector_type(4)));

#define NB 8192
#define NENC 4096
#define NH 128
#define NL 10
#define NT 12
#define PAD 136

// ---- workspace layout (element offsets in halfs unless noted) ----
#define OFF_FCIN 0                    // packed fc_in_W  [128 x 4096] fp16
#define SZ_FCIN (128*4096)
#define OFF_W (OFF_FCIN + SZ_FCIN)    // packed Wih/Whh  [10][2][512 x 128] fp16
#define SZ_W (10*2*512*128)
#define OFF_FCOUT (OFF_W + SZ_W)      // packed fc_out_W [80 x 128] fp16
#define SZ_FCOUT (80*128)
#define OFF_ENC (OFF_FCOUT + SZ_FCOUT) // enc (relu(fc_in)) [8192 x 128] fp16
#define SZ_ENC (8192*128)
#define OFF_GX0 (OFF_ENC + SZ_ENC)    // GX0 = enc@Wih0^T + b0, lane-layout fp16
#define SZ_GX0 (8192*512)
#define BYTE_BIAS ((OFF_GX0 + SZ_GX0)*2) // combined bias [10][512] f32 (byte offset)
// total ws usage: ~14.2 MB

__device__ __forceinline__ f4 splat4(float v) { f4 r; r[0]=v; r[1]=v; r[2]=v; r[3]=v; return r; }
__device__ __forceinline__ h8 cvt8(float4 a, float4 b) {
  h8 r; r[0]=(h16)a.x; r[1]=(h16)a.y; r[2]=(h16)a.z; r[3]=(h16)a.w;
  r[4]=(h16)b.x; r[5]=(h16)b.y; r[6]=(h16)b.z; r[7]=(h16)b.w; return r;
}

// Fused LSTM cell update. Exact algebra:
//   c' = c*sig(f) + sig(i)*tanh(g) = (c*ai*ag + af*(1-eg)) / (af*ai*ag)
//   h  = sig(o)*tanh(c')           = (1-ec) / (ao*ac)
// where ex = exp(-x) (exp(-2x) for the tanh args), ax = 1+ex.
// 5 exp2 + 2 rcp per element (was 5 exp2 + 5 rcp).
__device__ __forceinline__ h16 cell(float iv, float fv, float gv, float ov, float& c) {
  float ei = __builtin_amdgcn_exp2f(-1.4426950408889634f * iv);
  float ef = __builtin_amdgcn_exp2f(-1.4426950408889634f * fv);
  float eg = __builtin_amdgcn_exp2f(-2.8853900817779268f * gv);
  float eo = __builtin_amdgcn_exp2f(-1.4426950408889634f * ov);
  float ai = 1.f + ei, af = 1.f + ef, ag = 1.f + eg;
  float m1 = ai * ag;
  float R1 = __builtin_amdgcn_rcpf(af * m1);
  float cc = R1 * fmaf(af, 1.f - eg, c * m1);
  c = cc;
  float ec = __builtin_amdgcn_exp2f(-2.8853900817779268f * cc);
  float R2 = __builtin_amdgcn_rcpf((1.f + eo) * (1.f + ec));
  return (h16)(R2 * (1.f - ec));
}

// ---------------- prep: convert + pack weights (8 elems/thread) ----------------
__global__ __launch_bounds__(256) void prep(const float* __restrict__ fcinW,
                                            const float* __restrict__ Wih,
                                            const float* __restrict__ Whh,
                                            const float* __restrict__ bih,
                                            const float* __restrict__ bhh,
                                            const float* __restrict__ fcoutW,
                                            h16* __restrict__ wsh,
                                            float* __restrict__ wbias) {
  int idx = blockIdx.x * 256 + threadIdx.x;
  if (idx < 65536) {                          // fc_in_W [128][4096], Kd8=512
    int r = idx >> 9, k8 = idx & 511;
    const float* src = fcinW + r * 4096 + k8 * 8;
    h8 v = cvt8(*(const float4*)src, *(const float4*)(src + 4));
    *(h8*)(wsh + OFF_FCIN + (((r >> 4) * 512 + k8) * 128 + (r & 15) * 8)) = v;
  } else if (idx < 229376) {                  // Wih/Whh [10][512][128], Kd8=16
    int rel = idx - 65536;
    int l = rel >> 14, rr = rel & 16383;
    int ssel = rr >> 13, rk8 = rr & 8191;
    int r = rk8 >> 4, k8 = rk8 & 15;
    const float* src = (ssel ? Whh : Wih) + l * 65536 + r * 128 + k8 * 8;
    h8 v = cvt8(*(const float4*)src, *(const float4*)(src + 4));
    *(h8*)(wsh + OFF_W + (l * 2 + ssel) * 65536 +
           (((r >> 4) * 16 + k8) * 128 + (r & 15) * 8)) = v;
  } else if (idx < 230656) {                  // fc_out_W padded to [80][128]
    int rel = idx - 229376;
    int r = rel >> 4, k8 = rel & 15;
    h8 v;
    if (r < 75) {
      const float* src = fcoutW + r * 128 + k8 * 8;
      v = cvt8(*(const float4*)src, *(const float4*)(src + 4));
    } else {
      for (int j = 0; j < 8; ++j) v[j] = (h16)0.f;
    }
    *(h8*)(wsh + OFF_FCOUT + (((r >> 4) * 16 + k8) * 128 + (r & 15) * 8)) = v;
  } else if (idx < 235776) {
    int rel = idx - 230656;
    wbias[rel] = bih[rel] + bhh[rel];
  }
}

// ---------------- fc_in GEMM: enc = relu(A @ W^T + b), fp16 out ----------------
__global__ __launch_bounds__(256) void kin(const float* __restrict__ A,
                                           const float* __restrict__ bvec,
                                           h16* __restrict__ wsh) {
  const h16* Wp = wsh + OFF_FCIN;
  h16* ench = wsh + OFF_ENC;
  int tid = threadIdx.x;
  int w = tid >> 6, lane = tid & 63, s = lane & 15, q = lane >> 4;
  int m0 = blockIdx.x * 16;
  int c0 = w * 32 + s, c1 = c0 + 16;
  f4 acc0 = splat4(bvec[c0]);
  f4 acc1 = splat4(bvec[c1]);
  const float* arow = A + (size_t)(m0 + s) * NENC;
  const h16* wp0 = Wp + (w * 2 + 0) * (512 * 128) + s * 8;
  const h16* wp1 = Wp + (w * 2 + 1) * (512 * 128) + s * 8;
#pragma unroll 4
  for (int kb = 0; kb < 128; ++kb) {
    int k0 = kb * 32 + q * 8;
    float4 x0 = *(const float4*)(arow + k0);
    float4 x1 = *(const float4*)(arow + k0 + 4);
    h8 af = cvt8(x0, x1);
    h8 b0 = *(const h8*)(wp0 + (kb * 4 + q) * 128);
    h8 b1 = *(const h8*)(wp1 + (kb * 4 + q) * 128);
    acc0 = __builtin_amdgcn_mfma_f32_16x16x32_f16(af, b0, acc0, 0, 0, 0);
    acc1 = __builtin_amdgcn_mfma_f32_16x16x32_f16(af, b1, acc1, 0, 0, 0);
  }
#pragma unroll
  for (int r = 0; r < 4; ++r) {
    int b = m0 + q * 4 + r;
    float v0 = acc0[r]; v0 = v0 > 0.f ? v0 : 0.f;
    float v1 = acc1[r]; v1 = v1 > 0.f ? v1 : 0.f;
    ench[(size_t)b * NH + c0] = (h16)v0;
    ench[(size_t)b * NH + c1] = (h16)v1;
  }
}

// ---------------- kin2: GX0 = enc @ Wih0^T + b0 (t-invariant layer-0 x-GEMM) ----
// grid 2048 = [lb 256][mt 2][cg 4], block 256 (4 waves x 2 unit-blocks).
// Output layout matches lstm's lane order: [lb][W 8][g*2+mt][lane][r] fp16.
__global__ __launch_bounds__(256) void kin2(h16* __restrict__ wsh,
                                            const float* __restrict__ wbias) {
  int tid = threadIdx.x;
  int w2 = tid >> 6, lane = tid & 63, s = lane & 15, q = lane >> 4;
  int bid = blockIdx.x;
  int lb = bid >> 3, mt = (bid >> 2) & 1, cg = bid & 3;
  const h16* ench = wsh + OFF_ENC;
  const h16* wih0 = wsh + OFF_W;
  h16* gx0 = wsh + OFF_GX0;
  const h16* arow = ench + (size_t)(lb * 32 + mt * 16 + s) * NH;
  h8 ax[4];
#pragma unroll
  for (int kt = 0; kt < 4; ++kt) ax[kt] = *(const h8*)(arow + kt * 32 + q * 8);
#pragma unroll
  for (int ti = 0; ti < 2; ++ti) {
    int W = w2 * 2 + ti;
    int rb = cg * 8 + W;
    f4 acc = splat4(wbias[cg * 128 + W * 16 + s]);
#pragma unroll
    for (int kt = 0; kt < 4; ++kt) {
      h8 b = *(const h8*)(wih0 + (rb * 16 + kt * 4 + q) * 128 + s * 8);
      acc = __builtin_amdgcn_mfma_f32_16x16x32_f16(ax[kt], b, acc, 0, 0, 0);
    }
    h4 st; st[0] = (h16)acc[0]; st[1] = (h16)acc[1]; st[2] = (h16)acc[2]; st[3] = (h16)acc[3];
    *(h4*)(gx0 + ((((size_t)lb * 8 + W) * 8 + cg * 2 + mt) * 64 + lane) * 4) = st;
  }
}

// ---------------- persistent LSTM + output head ----------------
// grid 256 = 1 WG/CU, block 512 = 8 waves (2/SIMD), 32 batch rows/WG.
// 13-slot LDS ring as before (one barrier per (l,t)).
// NEW: layers 1..9 are software-pipelined one step ahead on the x-GEMM:
//   iter t: barrier -> h-GEMM(t-1) into acc (acc entered holding bias+x(t))
//           -> fused nonlinearity(t) (5 exp2 + 2 rcp / elem, was 10 trans)
//           -> acc := bias; x-GEMM(t+1)   [independent of the nonlinearity ->
//              MFMAs + ds_reads can fill the transcendental stall slots]
// x(t+1)'s ring slot (rw+2) is not overwritten until step t+2, so the early
// read is race-free under the single per-step barrier. t=11 computes a
// discarded garbage x-GEMM to keep the block branchless (slot rw+2 != rw).
__global__ __launch_bounds__(512, 2) void lstm(h16* __restrict__ wsh,
                                               const float* __restrict__ wbias,
                                               const float* __restrict__ fcoutb,
                                               float* __restrict__ out) {
  __shared__ h16 ring[13][32][PAD];   // 113152 B
  __shared__ float probst[32 * 26];
  int tid = threadIdx.x;
  int w = tid >> 6, lane = tid & 63, s = lane & 15, q = lane >> 4;
  int brow = blockIdx.x * 32;
  h8 wx[4][4], wh[4][4];
  float bb[4];
  float c[2][4];

  // ---------- layer 0: acc starts from GX0 (regs), no x-MFMAs ----------
  {
    const h16* whh = wsh + OFF_W + 65536;
#pragma unroll
    for (int g = 0; g < 4; ++g)
#pragma unroll
      for (int kt = 0; kt < 4; ++kt)
        wh[g][kt] = *(const h8*)(whh + (((g * 8 + w) * 16 + kt * 4 + q) * 128) + s * 8);
    f4 gx[4][2];
    const h16* gxp = wsh + OFF_GX0 + ((size_t)blockIdx.x * 8 + w) * 8 * 256 + (size_t)lane * 4;
#pragma unroll
    for (int g = 0; g < 4; ++g)
#pragma unroll
      for (int mt = 0; mt < 2; ++mt) {
        h4 v = *(const h4*)(gxp + (g * 2 + mt) * 256);
        f4 a; a[0] = (float)v[0]; a[1] = (float)v[1]; a[2] = (float)v[2]; a[3] = (float)v[3];
        gx[g][mt] = a;
      }
#pragma unroll
    for (int mt = 0; mt < 2; ++mt)
#pragma unroll
      for (int r = 0; r < 4; ++r) c[mt][r] = 0.f;
    for (int t = 0; t < NT; ++t) {
      __syncthreads();
      int rw = t + 11; if (rw >= 13) rw -= 13;
      int rh = t + 10; if (rh >= 13) rh -= 13;
      f4 acc[4][2];
#pragma unroll
      for (int g = 0; g < 4; ++g)
#pragma unroll
        for (int mt = 0; mt < 2; ++mt) acc[g][mt] = gx[g][mt];
      if (t > 0) {
#pragma unroll
        for (int mt = 0; mt < 2; ++mt) {
          h8 ah[4];
#pragma unroll
          for (int kt = 0; kt < 4; ++kt)
            ah[kt] = *(const h8*)&ring[rh][mt * 16 + s][kt * 32 + q * 8];
#pragma unroll
          for (int g = 0; g < 4; ++g)
#pragma unroll
            for (int kt = 0; kt < 4; ++kt)
              acc[g][mt] = __builtin_amdgcn_mfma_f32_16x16x32_f16(ah[kt], wh[g][kt], acc[g][mt], 0, 0, 0);
        }
      }
#pragma unroll
      for (int mt = 0; mt < 2; ++mt)
#pragma unroll
        for (int r = 0; r < 4; ++r) {
          h16 hv = cell(acc[0][mt][r], acc[1][mt][r], acc[2][mt][r], acc[3][mt][r], c[mt][r]);
          ring[rw][mt * 16 + q * 4 + r][w * 16 + s] = hv;
        }
    }
  }
  // ---------- layers 1..9 (x-GEMM pipelined one step ahead) ----------
  for (int l = 1; l < NL; ++l) {
    const h16* wih = wsh + OFF_W + (size_t)(l * 2) * 65536;
    const h16* whh = wih + 65536;
#pragma unroll
    for (int g = 0; g < 4; ++g) {
#pragma unroll
      for (int kt = 0; kt < 4; ++kt) {
        int off = (((g * 8 + w) * 16 + kt * 4 + q) * 128) + s * 8;
        wx[g][kt] = *(const h8*)(wih + off);
        wh[g][kt] = *(const h8*)(whh + off);
      }
      bb[g] = wbias[l * 512 + g * 128 + w * 16 + s];
    }
    f4 acc[4][2];
#pragma unroll
    for (int g = 0; g < 4; ++g)
#pragma unroll
      for (int mt = 0; mt < 2; ++mt) acc[g][mt] = splat4(bb[g]);
#pragma unroll
    for (int mt = 0; mt < 2; ++mt)
#pragma unroll
      for (int r = 0; r < 4; ++r) c[mt][r] = 0.f;
    for (int t = 0; t < NT; ++t) {
      __syncthreads();
      int rw = t + 11 - l; if (rw >= 13) rw -= 13;
      // phase 1: complete gates(t). acc entered holding bias + x(t)
      // (from the previous iteration's pipelined x-GEMM, or bias-only at t=0).
      if (t == 0) {
        int rr = rw + 1; if (rr >= 13) rr -= 13;   // x(0) slot
#pragma unroll
        for (int mt = 0; mt < 2; ++mt) {
          h8 ax[4];
#pragma unroll
          for (int kt = 0; kt < 4; ++kt)
            ax[kt] = *(const h8*)&ring[rr][mt * 16 + s][kt * 32 + q * 8];
#pragma unroll
          for (int g = 0; g < 4; ++g)
#pragma unroll
            for (int kt = 0; kt < 4; ++kt)
              acc[g][mt] = __builtin_amdgcn_mfma_f32_16x16x32_f16(ax[kt], wx[g][kt], acc[g][mt], 0, 0, 0);
        }
      } else {
        int rh = rw - 1; if (rh < 0) rh += 13;     // h(t-1) slot
#pragma unroll
        for (int mt = 0; mt < 2; ++mt) {
          h8 ah[4];
#pragma unroll
          for (int kt = 0; kt < 4; ++kt)
            ah[kt] = *(const h8*)&ring[rh][mt * 16 + s][kt * 32 + q * 8];
#pragma unroll
          for (int g = 0; g < 4; ++g)
#pragma unroll
            for (int kt = 0; kt < 4; ++kt)
              acc[g][mt] = __builtin_amdgcn_mfma_f32_16x16x32_f16(ah[kt], wh[g][kt], acc[g][mt], 0, 0, 0);
        }
      }
      // phase 2: nonlinearity(t) + pipelined x-GEMM(t+1) into reinit'd acc.
      int rx = rw + 2; if (rx >= 13) rx -= 13;     // x(t+1) slot (garbage at t=11)
#pragma unroll
      for (int mt = 0; mt < 2; ++mt) {
        h8 axn[4];
#pragma unroll
        for (int kt = 0; kt < 4; ++kt)
          axn[kt] = *(const h8*)&ring[rx][mt * 16 + s][kt * 32 + q * 8];
        h16 hv[4];
#pragma unroll
        for (int r = 0; r < 4; ++r)
          hv[r] = cell(acc[0][mt][r], acc[1][mt][r], acc[2][mt][r], acc[3][mt][r], c[mt][r]);
#pragma unroll
        for (int g = 0; g < 4; ++g) acc[g][mt] = splat4(bb[g]);
#pragma unroll
        for (int g = 0; g < 4; ++g)
#pragma unroll
          for (int kt = 0; kt < 4; ++kt)
            acc[g][mt] = __builtin_amdgcn_mfma_f32_16x16x32_f16(axn[kt], wx[g][kt], acc[g][mt], 0, 0, 0);
#pragma unroll
        for (int r = 0; r < 4; ++r)
          ring[rw][mt * 16 + q * 4 + r][w * 16 + s] = hv[r];
      }
    }
  }
  // ---- output head: layer-9 h(t) lives in ring slot (t+2)%13 ----
  __syncthreads();
  h8 wo[5][4];
  float bo[5];
  const h16* fco = wsh + OFF_FCOUT;
#pragma unroll
  for (int nt = 0; nt < 5; ++nt) {
#pragma unroll
    for (int kt = 0; kt < 4; ++kt)
      wo[nt][kt] = *(const h8*)(fco + (nt * 16 + kt * 4 + q) * 128 + s * 8);
    int col = nt * 16 + s;
    bo[nt] = (col < 75) ? fcoutb[col] : 0.f;
  }
  int tcount = (w < 4) ? 2 : 1;
  for (int ti = 0; ti < tcount; ++ti) {
    int t = w + ti * 8;
    int sl = t + 2; if (sl >= 13) sl -= 13;
#pragma unroll
    for (int mt = 0; mt < 2; ++mt) {
      h8 ax[4];
#pragma unroll
      for (int kt = 0; kt < 4; ++kt)
        ax[kt] = *(const h8*)&ring[sl][mt * 16 + s][kt * 32 + q * 8];
#pragma unroll
      for (int nt = 0; nt < 5; ++nt) {
        f4 a = splat4(bo[nt]);
#pragma unroll
        for (int kt = 0; kt < 4; ++kt)
          a = __builtin_amdgcn_mfma_f32_16x16x32_f16(ax[kt], wo[nt][kt], a, 0, 0, 0);
        int col = nt * 16 + s;
#pragma unroll
        for (int r = 0; r < 4; ++r) {
          int row = mt * 16 + q * 4 + r;
          int b = brow + row;
          float v = a[r];
          if (col < 50)
            out[(size_t)b * 600 + (col >> 1) * 24 + t * 2 + (col & 1)] = v;
          if (t == 11 && col >= 50 && col < 75)
            probst[row * 26 + (col - 50)] = v;
        }
      }
    }
  }
  __syncthreads();
  if (tid < 32) {
    float vals[25];
    float m = -1e30f;
#pragma unroll
    for (int j = 0; j < 25; ++j) { vals[j] = probst[tid * 26 + j]; m = vals[j] > m ? vals[j] : m; }
    float sum = 0.f;
#pragma unroll
    for (int j = 0; j < 25; ++j) {
      float e = __builtin_amdgcn_exp2f((vals[j] - m) * 1.4426950408889634f);
      vals[j] = e; sum += e;
    }
    float rs = 1.0f / sum;
    size_t pb = (size_t)4915200 + (size_t)(brow + tid) * 25;
#pragma unroll
    for (int j = 0; j < 25; ++j) out[pb + j] = vals[j] * rs;
  }
}

extern "C" void kernel_launch(void* const* d_in, const int* in_sizes, int n_in,
                              void* d_out, int out_size, void* d_ws, size_t ws_size,
                              hipStream_t stream) {
  const float* backbone = (const float*)d_in[0];
  const float* fcinW    = (const float*)d_in[1];
  const float* fcinb    = (const float*)d_in[2];
  const float* Wih      = (const float*)d_in[3];
  const float* Whh      = (const float*)d_in[4];
  const float* bih      = (const float*)d_in[5];
  const float* bhh      = (const float*)d_in[6];
  const float* fcoutW   = (const float*)d_in[7];
  const float* fcoutb   = (const float*)d_in[8];
  h16* wsh = (h16*)d_ws;
  float* wbias = (float*)((char*)d_ws + BYTE_BIAS);

  prep<<<922, 256, 0, stream>>>(fcinW, Wih, Whh, bih, bhh, fcoutW, wsh, wbias);
  kin<<<512, 256, 0, stream>>>(backbone, fcinb, wsh);
  kin2<<<2048, 256, 0, stream>>>(wsh, wbias);
  lstm<<<256, 512, 0, stream>>>(wsh, wbias, fcoutb, (float*)d_out);
}

// Round 2
// 494.128 us; speedup vs baseline: 1.0202x; 1.0092x over previous
//
#include <hip/hip_runtime.h>

typedef _Float16 h16;
typedef _Float16 h4 __attribute__((ext_vector_type(4)));
typedef _Float16 h8 __attribute__((ext_vector_type(8)));
typedef float f4 __attribute__((ext_vector_type(4)));

#define NB 8192
#define NENC 4096
#define NH 128
#define NL 10
#define NT 12
#define PAD 136
#define L2E 1.4426950408889634f
#define K2 -2.8853900817779268f

// ---- workspace layout (element offsets in halfs unless noted) ----
#define OFF_FCIN 0                    // packed fc_in_W  [128 x 4096] fp16
#define SZ_FCIN (128*4096)
#define OFF_W (OFF_FCIN + SZ_FCIN)    // packed Wih/Whh  [10][2][512 x 128] fp16, PRE-SCALED
#define SZ_W (10*2*512*128)
#define OFF_FCOUT (OFF_W + SZ_W)      // packed fc_out_W [80 x 128] fp16
#define SZ_FCOUT (80*128)
#define OFF_ENC (OFF_FCOUT + SZ_FCOUT) // enc (relu(fc_in)) [8192 x 128] fp16
#define SZ_ENC (8192*128)
#define OFF_GX0 (OFF_ENC + SZ_ENC)    // GX0 = enc@Wih0^T + b0 (scaled), lane-layout fp16
#define SZ_GX0 (8192*512)
#define BYTE_BIAS ((OFF_GX0 + SZ_GX0)*2) // combined bias [10][512] f32, PRE-SCALED (byte offset)

__device__ __forceinline__ f4 splat4(float v) { f4 r; r[0]=v; r[1]=v; r[2]=v; r[3]=v; return r; }
__device__ __forceinline__ h8 cvt8(float4 a, float4 b) {
  h8 r; r[0]=(h16)a.x; r[1]=(h16)a.y; r[2]=(h16)a.z; r[3]=(h16)a.w;
  r[4]=(h16)b.x; r[5]=(h16)b.y; r[6]=(h16)b.z; r[7]=(h16)b.w; return r;
}
__device__ __forceinline__ h8 cvt8s(float4 a, float4 b, float sc) {
  h8 r; r[0]=(h16)(a.x*sc); r[1]=(h16)(a.y*sc); r[2]=(h16)(a.z*sc); r[3]=(h16)(a.w*sc);
  r[4]=(h16)(b.x*sc); r[5]=(h16)(b.y*sc); r[6]=(h16)(b.z*sc); r[7]=(h16)(b.w*sc); return r;
}

// Fused LSTM cell with PRE-SCALED gate pre-activations:
//   iv = -log2e*i, fv = -log2e*f, gv = -2log2e*g, ov = -log2e*o
// so ei = 2^iv = e^-i etc. Exact algebra:
//   c' = (c*ai*ag + af*(1-eg)) / (af*ai*ag);  h = (1-ec)/(ao*ac)
// 5 exp2 + 2 rcp + 1 const-mul per element.
__device__ __forceinline__ h16 cell(float iv, float fv, float gv, float ov, float& c) {
  float ei = __builtin_amdgcn_exp2f(iv);
  float ef = __builtin_amdgcn_exp2f(fv);
  float eg = __builtin_amdgcn_exp2f(gv);
  float eo = __builtin_amdgcn_exp2f(ov);
  float ai = 1.f + ei, af = 1.f + ef, ag = 1.f + eg;
  float m1 = ai * ag;
  float R1 = __builtin_amdgcn_rcpf(af * m1);
  float cc = R1 * fmaf(af, 1.f - eg, c * m1);
  c = cc;
  float ec = __builtin_amdgcn_exp2f(K2 * cc);
  float R2 = __builtin_amdgcn_rcpf((1.f + eo) * (1.f + ec));
  return (h16)(R2 * (1.f - ec));
}

// ---------------- prep: convert + pack weights (8 elems/thread) ----------------
__global__ __launch_bounds__(256) void prep(const float* __restrict__ fcinW,
                                            const float* __restrict__ Wih,
                                            const float* __restrict__ Whh,
                                            const float* __restrict__ bih,
                                            const float* __restrict__ bhh,
                                            const float* __restrict__ fcoutW,
                                            h16* __restrict__ wsh,
                                            float* __restrict__ wbias) {
  int idx = blockIdx.x * 256 + threadIdx.x;
  if (idx < 65536) {                          // fc_in_W [128][4096], Kd8=512
    int r = idx >> 9, k8 = idx & 511;
    const float* src = fcinW + r * 4096 + k8 * 8;
    h8 v = cvt8(*(const float4*)src, *(const float4*)(src + 4));
    *(h8*)(wsh + OFF_FCIN + (((r >> 4) * 512 + k8) * 128 + (r & 15) * 8)) = v;
  } else if (idx < 229376) {                  // Wih/Whh [10][512][128], Kd8=16, pre-scaled
    int rel = idx - 65536;
    int l = rel >> 14, rr = rel & 16383;
    int ssel = rr >> 13, rk8 = rr & 8191;
    int r = rk8 >> 4, k8 = rk8 & 15;
    float sc = ((r >> 7) == 2) ? (-2.f * L2E) : (-L2E);
    const float* src = (ssel ? Whh : Wih) + l * 65536 + r * 128 + k8 * 8;
    h8 v = cvt8s(*(const float4*)src, *(const float4*)(src + 4), sc);
    *(h8*)(wsh + OFF_W + (l * 2 + ssel) * 65536 +
           (((r >> 4) * 16 + k8) * 128 + (r & 15) * 8)) = v;
  } else if (idx < 230656) {                  // fc_out_W padded to [80][128]
    int rel = idx - 229376;
    int r = rel >> 4, k8 = rel & 15;
    h8 v;
    if (r < 75) {
      const float* src = fcoutW + r * 128 + k8 * 8;
      v = cvt8(*(const float4*)src, *(const float4*)(src + 4));
    } else {
      for (int j = 0; j < 8; ++j) v[j] = (h16)0.f;
    }
    *(h8*)(wsh + OFF_FCOUT + (((r >> 4) * 16 + k8) * 128 + (r & 15) * 8)) = v;
  } else if (idx < 235776) {
    int rel = idx - 230656;
    int col = rel & 511;
    float sc = ((col >> 7) == 2) ? (-2.f * L2E) : (-L2E);
    wbias[rel] = (bih[rel] + bhh[rel]) * sc;
  }
}

// ---------------- fc_in GEMM: enc = relu(A @ W^T + b), fp16 out ----------------
__global__ __launch_bounds__(256) void kin(const float* __restrict__ A,
                                           const float* __restrict__ bvec,
                                           h16* __restrict__ wsh) {
  const h16* Wp = wsh + OFF_FCIN;
  h16* ench = wsh + OFF_ENC;
  int tid = threadIdx.x;
  int w = tid >> 6, lane = tid & 63, s = lane & 15, q = lane >> 4;
  int m0 = blockIdx.x * 16;
  int c0 = w * 32 + s, c1 = c0 + 16;
  f4 acc0 = splat4(bvec[c0]);
  f4 acc1 = splat4(bvec[c1]);
  const float* arow = A + (size_t)(m0 + s) * NENC;
  const h16* wp0 = Wp + (w * 2 + 0) * (512 * 128) + s * 8;
  const h16* wp1 = Wp + (w * 2 + 1) * (512 * 128) + s * 8;
#pragma unroll 4
  for (int kb = 0; kb < 128; ++kb) {
    int k0 = kb * 32 + q * 8;
    float4 x0 = *(const float4*)(arow + k0);
    float4 x1 = *(const float4*)(arow + k0 + 4);
    h8 af = cvt8(x0, x1);
    h8 b0 = *(const h8*)(wp0 + (kb * 4 + q) * 128);
    h8 b1 = *(const h8*)(wp1 + (kb * 4 + q) * 128);
    acc0 = __builtin_amdgcn_mfma_f32_16x16x32_f16(af, b0, acc0, 0, 0, 0);
    acc1 = __builtin_amdgcn_mfma_f32_16x16x32_f16(af, b1, acc1, 0, 0, 0);
  }
#pragma unroll
  for (int r = 0; r < 4; ++r) {
    int b = m0 + q * 4 + r;
    float v0 = acc0[r]; v0 = v0 > 0.f ? v0 : 0.f;
    float v1 = acc1[r]; v1 = v1 > 0.f ? v1 : 0.f;
    ench[(size_t)b * NH + c0] = (h16)v0;
    ench[(size_t)b * NH + c1] = (h16)v1;
  }
}

// ---------------- kin2: GX0 = enc @ Wih0^T + b0 (t-invariant layer-0 x-GEMM) ----
// Weights and bias arrive PRE-SCALED, so GX0 is in exp2-ready space.
__global__ __launch_bounds__(256) void kin2(h16* __restrict__ wsh,
                                            const float* __restrict__ wbias) {
  int tid = threadIdx.x;
  int w2 = tid >> 6, lane = tid & 63, s = lane & 15, q = lane >> 4;
  int bid = blockIdx.x;
  int lb = bid >> 3, mt = (bid >> 2) & 1, cg = bid & 3;
  const h16* ench = wsh + OFF_ENC;
  const h16* wih0 = wsh + OFF_W;
  h16* gx0 = wsh + OFF_GX0;
  const h16* arow = ench + (size_t)(lb * 32 + mt * 16 + s) * NH;
  h8 ax[4];
#pragma unroll
  for (int kt = 0; kt < 4; ++kt) ax[kt] = *(const h8*)(arow + kt * 32 + q * 8);
#pragma unroll
  for (int ti = 0; ti < 2; ++ti) {
    int W = w2 * 2 + ti;
    int rb = cg * 8 + W;
    f4 acc = splat4(wbias[cg * 128 + W * 16 + s]);
#pragma unroll
    for (int kt = 0; kt < 4; ++kt) {
      h8 b = *(const h8*)(wih0 + (rb * 16 + kt * 4 + q) * 128 + s * 8);
      acc = __builtin_amdgcn_mfma_f32_16x16x32_f16(ax[kt], b, acc, 0, 0, 0);
    }
    h4 st; st[0] = (h16)acc[0]; st[1] = (h16)acc[1]; st[2] = (h16)acc[2]; st[3] = (h16)acc[3];
    *(h4*)(gx0 + ((((size_t)lb * 8 + W) * 8 + cg * 2 + mt) * 64 + lane) * 4) = st;
  }
}

// ---------------- persistent LSTM + output head ----------------
// grid 256 = 1 WG/CU, block 512 = 8 waves (2/SIMD), 32 batch rows/WG.
// Ring transposed to [row][slot][col]: slot stride = PAD halfs, so per-iter
// addressing is base + slot*PAD with all 16 reads / 8 writes using immediate
// DS offsets (row stride 3536 B, col steps 64 B fit the 16-bit immediate).
// Bias lives in persistent bbv[] registers used as the MFMA C-operand of the
// first x-GEMM MFMA (no acc-reinit movs). x-GEMM(0) hoisted before the t-loop
// (its slot was written 12 barriers earlier); t=11 skips the x-GEMM entirely.
__global__ __launch_bounds__(512, 2) void lstm(h16* __restrict__ wsh,
                                               const float* __restrict__ wbias,
                                               const float* __restrict__ fcoutb,
                                               float* __restrict__ out) {
  __shared__ h16 ring[32][13][PAD];   // 113152 B
  __shared__ float probst[32 * 26];
  int tid = threadIdx.x;
  int w = tid >> 6, lane = tid & 63, s = lane & 15, q = lane >> 4;
  int brow = blockIdx.x * 32;
  h8 wx[4][4], wh[4][4];
  f4 bbv[4];
  float c[2][4];
  // per-lane base pointers into the ring (halfs)
  h16* rd0 = &ring[s][0][q * 8];
  h16* rd1 = &ring[16 + s][0][q * 8];
  h16* wr0 = &ring[q * 4][0][w * 16 + s];
  h16* wr1 = &ring[16 + q * 4][0][w * 16 + s];
#define RSTRIDE (13 * PAD)   // row stride in halfs (3536 B)

  // ---------- layer 0: acc chains from register-resident GX0 ----------
  {
    const h16* whh = wsh + OFF_W + 65536;
#pragma unroll
    for (int g = 0; g < 4; ++g)
#pragma unroll
      for (int kt = 0; kt < 4; ++kt)
        wh[g][kt] = *(const h8*)(whh + (((g * 8 + w) * 16 + kt * 4 + q) * 128) + s * 8);
    f4 gx[4][2];
    const h16* gxp = wsh + OFF_GX0 + ((size_t)blockIdx.x * 8 + w) * 8 * 256 + (size_t)lane * 4;
#pragma unroll
    for (int g = 0; g < 4; ++g)
#pragma unroll
      for (int mt = 0; mt < 2; ++mt) {
        h4 v = *(const h4*)(gxp + (g * 2 + mt) * 256);
        f4 a; a[0] = (float)v[0]; a[1] = (float)v[1]; a[2] = (float)v[2]; a[3] = (float)v[3];
        gx[g][mt] = a;
      }
#pragma unroll
    for (int mt = 0; mt < 2; ++mt)
#pragma unroll
      for (int r = 0; r < 4; ++r) c[mt][r] = 0.f;
    // t = 0: cell directly on gx, write to slot 11
    {
      h16* q0 = wr0 + 11 * PAD;
      h16* q1 = wr1 + 11 * PAD;
#pragma unroll
      for (int mt = 0; mt < 2; ++mt) {
        h16* qq = mt ? q1 : q0;
#pragma unroll
        for (int r = 0; r < 4; ++r)
          qq[r * RSTRIDE] = cell(gx[0][mt][r], gx[1][mt][r], gx[2][mt][r], gx[3][mt][r], c[mt][r]);
      }
    }
    int rw = 12;
    for (int t = 1; t < NT; ++t) {
      __syncthreads();
      int rh = rw - 1; if (rh < 0) rh += 13;
      f4 acc[4][2];
      const h16* p0 = rd0 + rh * PAD;
      const h16* p1 = rd1 + rh * PAD;
#pragma unroll
      for (int mt = 0; mt < 2; ++mt) {
        const h16* pp = mt ? p1 : p0;
        h8 ah[4];
#pragma unroll
        for (int kt = 0; kt < 4; ++kt) ah[kt] = *(const h8*)(pp + kt * 32);
#pragma unroll
        for (int g = 0; g < 4; ++g) {
          acc[g][mt] = __builtin_amdgcn_mfma_f32_16x16x32_f16(ah[0], wh[g][0], gx[g][mt], 0, 0, 0);
#pragma unroll
          for (int kt = 1; kt < 4; ++kt)
            acc[g][mt] = __builtin_amdgcn_mfma_f32_16x16x32_f16(ah[kt], wh[g][kt], acc[g][mt], 0, 0, 0);
        }
      }
      h16* q0 = wr0 + rw * PAD;
      h16* q1 = wr1 + rw * PAD;
#pragma unroll
      for (int mt = 0; mt < 2; ++mt) {
        h16* qq = mt ? q1 : q0;
#pragma unroll
        for (int r = 0; r < 4; ++r)
          qq[r * RSTRIDE] = cell(acc[0][mt][r], acc[1][mt][r], acc[2][mt][r], acc[3][mt][r], c[mt][r]);
      }
      ++rw; if (rw >= 13) rw = 0;
    }
  }
  // ---------- layers 1..9 (x-GEMM pipelined one step ahead, bias-in-C) ----------
  for (int l = 1; l < NL; ++l) {
    const h16* wih = wsh + OFF_W + (size_t)(l * 2) * 65536;
    const h16* whh = wih + 65536;
#pragma unroll
    for (int g = 0; g < 4; ++g) {
#pragma unroll
      for (int kt = 0; kt < 4; ++kt) {
        int off = (((g * 8 + w) * 16 + kt * 4 + q) * 128) + s * 8;
        wx[g][kt] = *(const h8*)(wih + off);
        wh[g][kt] = *(const h8*)(whh + off);
      }
      bbv[g] = splat4(wbias[l * 512 + g * 128 + w * 16 + s]);
    }
#pragma unroll
    for (int mt = 0; mt < 2; ++mt)
#pragma unroll
      for (int r = 0; r < 4; ++r) c[mt][r] = 0.f;
    int rw = 11 - l;                 // rw(t=0), l<=9 so in [2,10]
    f4 acc[4][2];
    // hoisted x-GEMM(0): slot rw+1 was written 12 barriers ago, race-free.
    {
      const h16* p0 = rd0 + (rw + 1) * PAD;
      const h16* p1 = rd1 + (rw + 1) * PAD;
#pragma unroll
      for (int mt = 0; mt < 2; ++mt) {
        const h16* pp = mt ? p1 : p0;
        h8 ax[4];
#pragma unroll
        for (int kt = 0; kt < 4; ++kt) ax[kt] = *(const h8*)(pp + kt * 32);
#pragma unroll
        for (int g = 0; g < 4; ++g) {
          acc[g][mt] = __builtin_amdgcn_mfma_f32_16x16x32_f16(ax[0], wx[g][0], bbv[g], 0, 0, 0);
#pragma unroll
          for (int kt = 1; kt < 4; ++kt)
            acc[g][mt] = __builtin_amdgcn_mfma_f32_16x16x32_f16(ax[kt], wx[g][kt], acc[g][mt], 0, 0, 0);
        }
      }
    }
    for (int t = 0; t < NT; ++t) {
      __syncthreads();
      if (t > 0) {                   // h-GEMM(t-1 state) chains into acc
        int rh = rw - 1; if (rh < 0) rh += 13;
        const h16* p0 = rd0 + rh * PAD;
        const h16* p1 = rd1 + rh * PAD;
#pragma unroll
        for (int mt = 0; mt < 2; ++mt) {
          const h16* pp = mt ? p1 : p0;
          h8 ah[4];
#pragma unroll
          for (int kt = 0; kt < 4; ++kt) ah[kt] = *(const h8*)(pp + kt * 32);
#pragma unroll
          for (int g = 0; g < 4; ++g)
#pragma unroll
            for (int kt = 0; kt < 4; ++kt)
              acc[g][mt] = __builtin_amdgcn_mfma_f32_16x16x32_f16(ah[kt], wh[g][kt], acc[g][mt], 0, 0, 0);
        }
      }
      // cell(t)
      h16 hv[2][4];
#pragma unroll
      for (int mt = 0; mt < 2; ++mt)
#pragma unroll
        for (int r = 0; r < 4; ++r)
          hv[mt][r] = cell(acc[0][mt][r], acc[1][mt][r], acc[2][mt][r], acc[3][mt][r], c[mt][r]);
      if (t < 11) {                  // pipelined x-GEMM(t+1), C = bias regs
        int rx = rw + 2; if (rx >= 13) rx -= 13;
        const h16* p0 = rd0 + rx * PAD;
        const h16* p1 = rd1 + rx * PAD;
#pragma unroll
        for (int mt = 0; mt < 2; ++mt) {
          const h16* pp = mt ? p1 : p0;
          h8 ax[4];
#pragma unroll
          for (int kt = 0; kt < 4; ++kt) ax[kt] = *(const h8*)(pp + kt * 32);
#pragma unroll
          for (int g = 0; g < 4; ++g) {
            acc[g][mt] = __builtin_amdgcn_mfma_f32_16x16x32_f16(ax[0], wx[g][0], bbv[g], 0, 0, 0);
#pragma unroll
            for (int kt = 1; kt < 4; ++kt)
              acc[g][mt] = __builtin_amdgcn_mfma_f32_16x16x32_f16(ax[kt], wx[g][kt], acc[g][mt], 0, 0, 0);
          }
        }
      }
      h16* q0 = wr0 + rw * PAD;
      h16* q1 = wr1 + rw * PAD;
#pragma unroll
      for (int mt = 0; mt < 2; ++mt) {
        h16* qq = mt ? q1 : q0;
#pragma unroll
        for (int r = 0; r < 4; ++r) qq[r * RSTRIDE] = hv[mt][r];
      }
      ++rw; if (rw >= 13) rw = 0;
    }
  }
  // ---- output head: layer-9 h(t) lives in ring slot (t+2)%13 ----
  __syncthreads();
  h8 wo[5][4];
  float bo[5];
  const h16* fco = wsh + OFF_FCOUT;
#pragma unroll
  for (int nt = 0; nt < 5; ++nt) {
#pragma unroll
    for (int kt = 0; kt < 4; ++kt)
      wo[nt][kt] = *(const h8*)(fco + (nt * 16 + kt * 4 + q) * 128 + s * 8);
    int col = nt * 16 + s;
    bo[nt] = (col < 75) ? fcoutb[col] : 0.f;
  }
  int tcount = (w < 4) ? 2 : 1;
  for (int ti = 0; ti < tcount; ++ti) {
    int t = w + ti * 8;
    int sl = t + 2; if (sl >= 13) sl -= 13;
#pragma unroll
    for (int mt = 0; mt < 2; ++mt) {
      const h16* pp = (mt ? rd1 : rd0) + sl * PAD;
      h8 ax[4];
#pragma unroll
      for (int kt = 0; kt < 4; ++kt) ax[kt] = *(const h8*)(pp + kt * 32);
#pragma unroll
      for (int nt = 0; nt < 5; ++nt) {
        f4 a = splat4(bo[nt]);
#pragma unroll
        for (int kt = 0; kt < 4; ++kt)
          a = __builtin_amdgcn_mfma_f32_16x16x32_f16(ax[kt], wo[nt][kt], a, 0, 0, 0);
        int col = nt * 16 + s;
#pragma unroll
        for (int r = 0; r < 4; ++r) {
          int row = mt * 16 + q * 4 + r;
          int b = brow + row;
          float v = a[r];
          if (col < 50)
            out[(size_t)b * 600 + (col >> 1) * 24 + t * 2 + (col & 1)] = v;
          if (t == 11 && col >= 50 && col < 75)
            probst[row * 26 + (col - 50)] = v;
        }
      }
    }
  }
  __syncthreads();
  if (tid < 32) {
    float vals[25];
    float m = -1e30f;
#pragma unroll
    for (int j = 0; j < 25; ++j) { vals[j] = probst[tid * 26 + j]; m = vals[j] > m ? vals[j] : m; }
    float sum = 0.f;
#pragma unroll
    for (int j = 0; j < 25; ++j) {
      float e = __builtin_amdgcn_exp2f((vals[j] - m) * L2E);
      vals[j] = e; sum += e;
    }
    float rs = 1.0f / sum;
    size_t pb = (size_t)4915200 + (size_t)(brow + tid) * 25;
#pragma unroll
    for (int j = 0; j < 25; ++j) out[pb + j] = vals[j] * rs;
  }
}

extern "C" void kernel_launch(void* const* d_in, const int* in_sizes, int n_in,
                              void* d_out, int out_size, void* d_ws, size_t ws_size,
                              hipStream_t stream) {
  const float* backbone = (const float*)d_in[0];
  const float* fcinW    = (const float*)d_in[1];
  const float* fcinb    = (const float*)d_in[2];
  const float* Wih      = (const float*)d_in[3];
  const float* Whh      = (const float*)d_in[4];
  const float* bih      = (const float*)d_in[5];
  const float* bhh      = (const float*)d_in[6];
  const float* fcoutW   = (const float*)d_in[7];
  const float* fcoutb   = (const float*)d_in[8];
  h16* wsh = (h16*)d_ws;
  float* wbias = (float*)((char*)d_ws + BYTE_BIAS);

  prep<<<922, 256, 0, stream>>>(fcinW, Wih, Whh, bih, bhh, fcoutW, wsh, wbias);
  kin<<<512, 256, 0, stream>>>(backbone, fcinb, wsh);
  kin2<<<2048, 256, 0, stream>>>(wsh, wbias);
  lstm<<<256, 512, 0, stream>>>(wsh, wbias, fcoutb, (float*)d_out);
}